// Round 3
// baseline (9905.537 us; speedup 1.0000x reference)
//
#include <hip/hip_runtime.h>
#include <hip/hip_bf16.h>
#include <stdint.h>

// LCA on MI355X, round 8. Residual form: r = x - a@w^T ; u += 0.01*(r@w + a - u);
// a = relu(u - 0.3). All GEMMs NT. Changes vs round 7 (passed, 9.87 ms):
//  - MODE 0/2 tile goes 128x64/TBK64 -> 128x128/TBK32 (m97 geometry, 64 FLOP/B
//    vs 42.7): round-7 counters showed conflicts=0 yet per-K cost identical to
//    round 5 -> staging-throughput/intensity bound, not latency/conflict bound.
//    Grid 64x7=448 blocks, fully co-resident (no tail round); LDS 32KB.
//    Round 4's BN=128 latency problem is addressed by the round-6/7 pipeline
//    (dbuf + counted vmcnt prefetches a full iteration ahead).
//  - MODE 1 unchanged (epilogue-HBM-bound at ~86% achievable).
//  - k-accumulation order unchanged -> numerics identical (absmax 0.015625).
// ws = u f32 (67.1MB) + r bf16 (13.1MB) + wT (3.3MB) + wB (3.2MB) + flag = 86.7MB.

typedef __bf16 bf16_t;
typedef float f32x4 __attribute__((ext_vector_type(4)));
typedef __bf16 bf16x8 __attribute__((ext_vector_type(8)));
typedef int int4v __attribute__((ext_vector_type(4)));

#define BM 128

static __device__ __forceinline__ f32x4 mfma16(int4v a, int4v b, f32x4 c) {
    return __builtin_amdgcn_mfma_f32_16x16x32_bf16(
        __builtin_bit_cast(bf16x8, a), __builtin_bit_cast(bf16x8, b), c, 0, 0, 0);
}

// async global->LDS, 16B/lane; LDS dest = wave-uniform base + lane*16.
static __device__ __forceinline__ void gl_lds16(const bf16_t* gp, bf16_t* lp) {
    auto g1 = (const __attribute__((address_space(1))) uint32_t*)(uintptr_t)gp;
    auto l3 = (__attribute__((address_space(3))) uint32_t*)(uintptr_t)lp;
    __builtin_amdgcn_global_load_lds(g1, l3, 16, 0, 0);
}

template <int N>
static __device__ __forceinline__ void vm_wait() {
    if constexpr (N == 0)      asm volatile("s_waitcnt vmcnt(0)" ::: "memory");
    else if constexpr (N == 4) asm volatile("s_waitcnt vmcnt(4)" ::: "memory");
    else if constexpr (N == 6) asm volatile("s_waitcnt vmcnt(6)" ::: "memory");
    else if constexpr (N == 8) asm volatile("s_waitcnt vmcnt(8)" ::: "memory");
    else                       static_assert(N == 0, "unsupported vmcnt");
}

// flag=1 iff inputs are fp32 (sniff even halfwords of w: fp32 mantissa bits
// look like huge-exponent bf16s; real bf16 |w|<=1 has exp field <= 0x7f).
__global__ void sniff(const uint16_t* __restrict__ wh, int* __restrict__ flag) {
    __shared__ int cnt;
    if (threadIdx.x == 0) cnt = 0;
    __syncthreads();
    int c = 0;
    for (int t = threadIdx.x; t < 4096; t += 256) {
        uint16_t h = wh[(size_t)2 * t * 97];
        c += (((h >> 7) & 0xFF) >= 0x82);
    }
    atomicAdd(&cnt, c);
    __syncthreads();
    if (threadIdx.x == 0) flag[0] = (cnt > 256) ? 1 : 0;
}

__global__ void fill0(int4v* __restrict__ p, long n16) {
    long i = (long)blockIdx.x * 256 + threadIdx.x;
    if (i < n16) p[i] = (int4v){0, 0, 0, 0};
}

// wB[k,j] = bf16(w[k,j]) for k<784;  wT[j,k] = wB[k,j], zero-padded to k<800
__global__ void build_w(const void* __restrict__ w, bf16_t* __restrict__ wT,
                        bf16_t* __restrict__ wB, const int* __restrict__ flag) {
    const int k = blockIdx.x * 256 + threadIdx.x;
    const int j = blockIdx.y;
    if (k >= 800) return;
    bf16_t v = (bf16_t)0.0f;
    if (k < 784) {
        v = flag[0] ? (bf16_t)((const float*)w)[(size_t)k * 2048 + j]
                    : ((const bf16_t*)w)[(size_t)k * 2048 + j];
        wB[(size_t)k * 2048 + j] = v;
    }
    wT[(size_t)j * 800 + k] = v;
}

// NT-GEMM  C[i,j] = sum_k A[i,k]*B[j,k].  Tile BM x BNT, K-step TBK.
// 2-phase double-buffered: stage tile t+1 via global_load_lds while computing
// tile t; counted s_waitcnt vmcnt(L) keeps next tile's loads in flight across
// the barrier. LDS chunk-XOR swizzle (chunk ^= row&(CPR-1), 16B granularity)
// applied on the global source AND the ds_read address (linear LDS dest).
// MODE 0 (R):    r[gm,gn] = x[gm,gn] - C   (gn<N; x dtype per flag)
// MODE 1 (STEP): uo=U; ao=relu(uo-.3); un=uo+0.01*(C+ao-uo); U=un; a=relu(un-.3)
// MODE 2 (REC):  Out[gm,gn] = bf16(C)  (gn<N)
template <int MODE, bool CLAMPN, int BNT, int TBK>
__global__ __launch_bounds__(256, 2) void gemm_nt(
    const bf16_t* __restrict__ A, const bf16_t* __restrict__ B,
    int N, int K, int lda, int ldb,
    const void* __restrict__ Xin, float* __restrict__ U,
    bf16_t* __restrict__ Out, int ldo, const int* __restrict__ flag)
{
    constexpr int NTC = BNT / 32;   // 16-wide n-tiles per wave
    constexpr int CPR = TBK / 8;    // 16B chunks per tile row
    constexpr int AL  = BM * CPR / 256;    // A staging insts per thread
    constexpr int BL  = BNT * CPR / 256;   // B staging insts per thread
    constexpr int L   = AL + BL;           // loads in flight per tile per wave
    constexpr int KH  = TBK / 32;          // k-halves per tile (MFMA K=32)

    __shared__ __align__(16) bf16_t sA[2][BM * TBK];
    __shared__ __align__(16) bf16_t sB[2][BNT * TBK];

    const int tid  = threadIdx.x;
    const int lane = tid & 63;
    const int wave = tid >> 6;
    const int wm   = wave >> 1;   // 2x2 wave grid
    const int wn   = wave & 1;
    const int bm   = blockIdx.x * BM;
    const int bn   = blockIdx.y * BNT;

    f32x4 acc[4][NTC];
#pragma unroll
    for (int i = 0; i < 4; ++i)
#pragma unroll
        for (int j = 0; j < NTC; ++j) acc[i][j] = (f32x4){0.f, 0.f, 0.f, 0.f};

    // staging map: chunk c = l*256+tid -> LDS row c/CPR, LDS chunk c%CPR,
    // LDS offset c*16B (linear). SOURCE chunk = (c%CPR) ^ (row & (CPR-1))
    // so that LDS[row][chunk] holds logical chunk (chunk ^ (row&(CPR-1))).
    const bf16_t* gA[AL];
    const bf16_t* gB[BL];
#pragma unroll
    for (int l = 0; l < AL; ++l) {
        const int c  = l * 256 + tid;
        const int rL = c / CPR;
        const int sc = (c & (CPR - 1)) ^ (rL & (CPR - 1));
        gA[l] = A + (size_t)(bm + rL) * lda + sc * 8;
    }
#pragma unroll
    for (int l = 0; l < BL; ++l) {
        const int c  = l * 256 + tid;
        const int rL = c / CPR;
        const int sc = (c & (CPR - 1)) ^ (rL & (CPR - 1));
        int rb = bn + rL;
        if (CLAMPN) rb = min(rb, N - 1);
        gB[l] = B + (size_t)rb * ldb + sc * 8;
    }

    auto stage = [&](int buf, int k0) {
#pragma unroll
        for (int l = 0; l < AL; ++l)
            gl_lds16(gA[l] + k0, &sA[buf][(size_t)(l * 256 + tid) * 8]);
#pragma unroll
        for (int l = 0; l < BL; ++l)
            gl_lds16(gB[l] + k0, &sB[buf][(size_t)(l * 256 + tid) * 8]);
    };

    const int mrow = lane & 15;
    const int q    = lane >> 4;
    // read-side swizzle: fragment row = 16*t_base + mrow, and 16 = 0 mod CPR,
    // so row&(CPR-1) == mrow&(CPR-1) -> per-lane constant.
    const int swz = mrow & (CPR - 1);
    const int qx  = q ^ (swz & 3);          // low 2 chunk bits
    const int ksw = (CPR > 4) ? (swz >> 2) : 0;  // chunk bit 2 (TBK=64 only)

    stage(0, 0);
    int cur = 0;
    for (int k0 = 0; k0 < K; k0 += TBK) {
        if (k0 + TBK < K) {
            stage(cur ^ 1, k0 + TBK);   // next tile's DMA in flight across barrier
            vm_wait<L>();               // wait only for CURRENT tile's L loads
        } else {
            vm_wait<0>();               // epilogue drain
        }
        __builtin_amdgcn_s_barrier();   // all waves' DMA for buf[cur] landed
        asm volatile("" ::: "memory");  // don't hoist ds_reads above barrier

        int4v af[4][KH], bv[NTC][KH];
        const bf16_t* pa = &sA[cur][(wm * 64 + mrow) * TBK + qx * 8];
        const bf16_t* pb = &sB[cur][(wn * (BNT / 2) + mrow) * TBK + qx * 8];
#pragma unroll
        for (int t = 0; t < 4; ++t)
#pragma unroll
            for (int kk = 0; kk < KH; ++kk)
                af[t][kk] = *(const int4v*)(pa + t * 16 * TBK + (kk ^ ksw) * 32);
#pragma unroll
        for (int t = 0; t < NTC; ++t)
#pragma unroll
            for (int kk = 0; kk < KH; ++kk)
                bv[t][kk] = *(const int4v*)(pb + t * 16 * TBK + (kk ^ ksw) * 32);
#pragma unroll
        for (int kk = 0; kk < KH; ++kk)       // logical k-order unchanged
#pragma unroll
            for (int mt = 0; mt < 4; ++mt)
#pragma unroll
                for (int nt = 0; nt < NTC; ++nt)
                    acc[mt][nt] = mfma16(af[mt][kk], bv[nt][kk], acc[mt][nt]);

        // all our ds_reads must COMPLETE before any wave passes the barrier
        // (next iter's DMA overwrites buf[cur]); MFMA sinking past is harmless.
        asm volatile("s_waitcnt lgkmcnt(0)" ::: "memory");
        __builtin_amdgcn_s_barrier();
        cur ^= 1;
    }

    int f = 0;
    if (MODE == 0) f = flag[0];

    // C/D layout: col = lane&15, row = (lane>>4)*4 + r   [m89/m91]
    const int coln = lane & 15;
    const int rq   = lane >> 4;
#pragma unroll
    for (int mt = 0; mt < 4; ++mt) {
#pragma unroll
        for (int r = 0; r < 4; ++r) {
            const int gm = bm + wm * 64 + mt * 16 + rq * 4 + r;
#pragma unroll
            for (int nt = 0; nt < NTC; ++nt) {
                const int gn = bn + wn * (BNT / 2) + nt * 16 + coln;
                const float c = acc[mt][nt][r];
                if (MODE == 0) {
                    if (gn < N) {
                        const size_t xi = (size_t)gm * N + gn;
                        const float xv = f ? ((const float*)Xin)[xi]
                                           : (float)((const bf16_t*)Xin)[xi];
                        Out[(size_t)gm * ldo + gn] = (bf16_t)(xv - c);
                    }
                } else if (MODE == 1) {
                    const size_t idx = (size_t)gm * ldo + gn;
                    const float uo = U[idx];
                    const float ao = fmaxf(uo - 0.3f, 0.0f);
                    const float un = uo + 0.01f * (c + ao - uo);
                    U[idx] = un;
                    Out[idx] = (bf16_t)fmaxf(un - 0.3f, 0.0f);
                } else {
                    if (gn < N)
                        Out[(size_t)gm * ldo + gn] = (bf16_t)c;
                }
            }
        }
    }
}

// fp32-output only: expand a (bf16, d_out scratch) into the fp32 a-region.
// Two passes with disjoint src/dst per pass (expansion-by-2 overlap split).
__global__ void a_move(const bf16_t* __restrict__ src, float* __restrict__ dst,
                       long lo, long hi, const int* __restrict__ flag) {
    if (!flag[0]) return;
    long i = lo + (long)blockIdx.x * 256 + threadIdx.x;
    if (i < hi) dst[i] = (float)src[i];
}

__global__ void recon_out(const bf16_t* __restrict__ rec, void* __restrict__ dout,
                          const int* __restrict__ flag) {
    long i = (long)blockIdx.x * 256 + threadIdx.x;
    if (i >= 6422528L) return;
    if (flag[0]) ((float*)dout)[i] = (float)rec[i];
    else         ((bf16_t*)dout)[i] = rec[i];
}

extern "C" void kernel_launch(void* const* d_in, const int* in_sizes, int n_in,
                              void* d_out, int out_size, void* d_ws, size_t ws_size,
                              hipStream_t stream) {
    const void* x = d_in[0];   // [8192, 784]  fp32 or bf16
    const void* w = d_in[1];   // [784, 2048]  fp32 or bf16
    (void)in_sizes; (void)n_in; (void)out_size; (void)ws_size;

    char* ws = (char*)d_ws;
    float*  u    = (float*)ws;                          // 67,108,864 B
    bf16_t* r    = (bf16_t*)(ws + 67108864);            // 13,107,200 B (8192x800)
    bf16_t* wT   = (bf16_t*)(ws + 80216064);            //  3,276,800 B (2048x800)
    bf16_t* wB   = (bf16_t*)(ws + 83492864);            //  3,211,264 B (784x2048)
    int*    flag = (int*)(ws + 86704128);               // total 86.7 MB
    bf16_t* aA   = (bf16_t*)((char*)d_out + 12845056);  // a scratch = bf16 a-region
    bf16_t* rec  = r;                                   // reuse r for recon temp

    sniff<<<1, 256, 0, stream>>>((const uint16_t*)w, flag);
    fill0<<<16384, 256, 0, stream>>>((int4v*)u, 4194304L);   // u = 0
    fill0<<<3200, 256, 0, stream>>>((int4v*)r, 819200L);     // r = 0 (incl. pad)
    fill0<<<8192, 256, 0, stream>>>((int4v*)aA, 2097152L);   // a = 0
    build_w<<<dim3(4, 2048), 256, 0, stream>>>(w, wT, wB, flag);

    // 99 LCA updates: r = x - a@w^T ; u += 0.01*(r@w + a - u); a = relu(u-0.3)
    for (int i = 0; i < 99; ++i) {
        gemm_nt<0, true, 128, 32><<<dim3(64, 7), 256, 0, stream>>>(
            aA, wB, 784, 2048, 2048, 2048, x, nullptr, r, 800, flag);
        gemm_nt<1, false, 128, 32><<<dim3(64, 16), 256, 0, stream>>>(
            r, wT, 2048, 800, 800, 800, nullptr, u, aA, 2048, flag);
    }

    // reconstruction = a @ w^T -> ws temp (bf16)
    gemm_nt<2, true, 128, 32><<<dim3(64, 7), 256, 0, stream>>>(
        aA, wB, 784, 2048, 2048, 2048, nullptr, nullptr, rec, 784, flag);

    // fp32 out: move a into fp32 a-region (race-free 2-pass split at 5,177,344)
    float* aOutF = (float*)d_out + 6422528;
    a_move<<<45312, 256, 0, stream>>>(aA, aOutF, 5177344L, 16777216L, flag);
    a_move<<<20224, 256, 0, stream>>>(aA, aOutF, 0L, 5177344L, flag);

    // recon -> d_out front, flag dtype (aA scratch dead by now in fp32 mode)
    recon_out<<<25088, 256, 0, stream>>>(rec, d_out, flag);
}

// Round 5
// 9388.093 us; speedup vs baseline: 1.0551x; 1.0551x over previous
//
#include <hip/hip_runtime.h>
#include <hip/hip_bf16.h>
#include <stdint.h>

// LCA on MI355X, round 10 (= round 9 resubmitted after MI355X container infra
// failure; no kernel change). Residual form: r = x - a@w^T ;
// u += 0.01*(r@w + a - u); a = relu(u - 0.3). All GEMMs NT.
// Changes vs round 8 (passed, 9.91 ms):
//  - MODE 0/2 keep the 128x128/TBK32 intensity but go to 512-thread blocks
//    (8 waves, 2x4 wave grid, per-wave 64x32 output): round-8 counters showed
//    occupancy 22->15% and staging rate 10.5->6.7 TB/s -- 448 blocks of 4
//    waves starved the CUs. Now 3584 waves (~14/CU), launch_bounds(512,4)
//    -> 2 blocks/CU. MODE 1 stays 256-thread (at its epilogue-HBM roofline).
//  - CPR=4 swizzle fold upgraded: chunk ^= (row ^ (row>>2)) & 3 (was row&3).
//    Old fold left a 4-way phase conflict (3.67M cycles); new fold is 2-way
//    (free per m136). Applies to both MODE 0 (TBK32) and MODE 1.
//  - k-accumulation order unchanged -> numerics identical (absmax 0.015625).
// ws = u f32 (67.1MB) + r bf16 (13.1MB) + wT (3.3MB) + wB (3.2MB) + flag = 86.7MB.

typedef __bf16 bf16_t;
typedef float f32x4 __attribute__((ext_vector_type(4)));
typedef __bf16 bf16x8 __attribute__((ext_vector_type(8)));
typedef int int4v __attribute__((ext_vector_type(4)));

#define BM 128

static __device__ __forceinline__ f32x4 mfma16(int4v a, int4v b, f32x4 c) {
    return __builtin_amdgcn_mfma_f32_16x16x32_bf16(
        __builtin_bit_cast(bf16x8, a), __builtin_bit_cast(bf16x8, b), c, 0, 0, 0);
}

// async global->LDS, 16B/lane; LDS dest = wave-uniform base + lane*16.
static __device__ __forceinline__ void gl_lds16(const bf16_t* gp, bf16_t* lp) {
    auto g1 = (const __attribute__((address_space(1))) uint32_t*)(uintptr_t)gp;
    auto l3 = (__attribute__((address_space(3))) uint32_t*)(uintptr_t)lp;
    __builtin_amdgcn_global_load_lds(g1, l3, 16, 0, 0);
}

template <int N>
static __device__ __forceinline__ void vm_wait() {
    if constexpr (N == 0)      asm volatile("s_waitcnt vmcnt(0)" ::: "memory");
    else if constexpr (N == 2) asm volatile("s_waitcnt vmcnt(2)" ::: "memory");
    else if constexpr (N == 4) asm volatile("s_waitcnt vmcnt(4)" ::: "memory");
    else if constexpr (N == 6) asm volatile("s_waitcnt vmcnt(6)" ::: "memory");
    else if constexpr (N == 8) asm volatile("s_waitcnt vmcnt(8)" ::: "memory");
    else                       static_assert(N == 0, "unsupported vmcnt");
}

// LDS chunk-swizzle fold. CPR=8: row&7 (proven 0-conflict, r7). CPR=4:
// (row ^ row>>2)&3 -> within a 16-lane ds_read_b128 phase, 16B-slot mod 8
// takes each value exactly twice = 2-way = free (m136); plain row&3 was 4-way.
template <int CPR>
static __device__ __forceinline__ int foldf(int r) {
    if constexpr (CPR == 8) return r & 7;
    else                    return (r ^ (r >> 2)) & 3;
}

// flag=1 iff inputs are fp32 (sniff even halfwords of w: fp32 mantissa bits
// look like huge-exponent bf16s; real bf16 |w|<=1 has exp field <= 0x7f).
__global__ void sniff(const uint16_t* __restrict__ wh, int* __restrict__ flag) {
    __shared__ int cnt;
    if (threadIdx.x == 0) cnt = 0;
    __syncthreads();
    int c = 0;
    for (int t = threadIdx.x; t < 4096; t += 256) {
        uint16_t h = wh[(size_t)2 * t * 97];
        c += (((h >> 7) & 0xFF) >= 0x82);
    }
    atomicAdd(&cnt, c);
    __syncthreads();
    if (threadIdx.x == 0) flag[0] = (cnt > 256) ? 1 : 0;
}

__global__ void fill0(int4v* __restrict__ p, long n16) {
    long i = (long)blockIdx.x * 256 + threadIdx.x;
    if (i < n16) p[i] = (int4v){0, 0, 0, 0};
}

// wB[k,j] = bf16(w[k,j]) for k<784;  wT[j,k] = wB[k,j], zero-padded to k<800
__global__ void build_w(const void* __restrict__ w, bf16_t* __restrict__ wT,
                        bf16_t* __restrict__ wB, const int* __restrict__ flag) {
    const int k = blockIdx.x * 256 + threadIdx.x;
    const int j = blockIdx.y;
    if (k >= 800) return;
    bf16_t v = (bf16_t)0.0f;
    if (k < 784) {
        v = flag[0] ? (bf16_t)((const float*)w)[(size_t)k * 2048 + j]
                    : ((const bf16_t*)w)[(size_t)k * 2048 + j];
        wB[(size_t)k * 2048 + j] = v;
    }
    wT[(size_t)j * 800 + k] = v;
}

// NT-GEMM  C[i,j] = sum_k A[i,k]*B[j,k].  Tile BM x BNT, K-step TBK, NW waves
// (wave grid 2 x NW/2; per-wave output 64 x BNT/(NW/2)).
// 2-phase double-buffered: stage tile t+1 via global_load_lds while computing
// tile t; counted s_waitcnt vmcnt(L) keeps next tile's loads in flight across
// the barrier. LDS chunk-XOR swizzle (chunk ^= foldf(row), 16B granularity)
// applied on the global source AND the ds_read address (linear LDS dest).
// MODE 0 (R):    r[gm,gn] = x[gm,gn] - C   (gn<N; x dtype per flag)
// MODE 1 (STEP): uo=U; ao=relu(uo-.3); un=uo+0.01*(C+ao-uo); U=un; a=relu(un-.3)
// MODE 2 (REC):  Out[gm,gn] = bf16(C)  (gn<N)
template <int MODE, bool CLAMPN, int BNT, int TBK, int NW>
__global__ __launch_bounds__(NW * 64, NW / 2) void gemm_nt(
    const bf16_t* __restrict__ A, const bf16_t* __restrict__ B,
    int N, int K, int lda, int ldb,
    const void* __restrict__ Xin, float* __restrict__ U,
    bf16_t* __restrict__ Out, int ldo, const int* __restrict__ flag)
{
    constexpr int THREADS = NW * 64;
    constexpr int NWN = NW / 2;            // wave-grid cols (2 rows of waves)
    constexpr int MT  = 4;                 // 16-row m-tiles per wave (BM/32)
    constexpr int NTW = BNT / (NWN * 16);  // 16-col n-tiles per wave
    constexpr int CPR = TBK / 8;           // 16B chunks per tile row
    constexpr int AL  = BM * CPR / THREADS;    // A staging insts per thread
    constexpr int BL  = BNT * CPR / THREADS;   // B staging insts per thread
    constexpr int L   = AL + BL;           // loads in flight per tile per wave
    constexpr int KH  = TBK / 32;          // k-halves per tile (MFMA K=32)
    static_assert(AL >= 1 && BL >= 1 && NTW >= 1, "geometry");

    __shared__ __align__(16) bf16_t sA[2][BM * TBK];
    __shared__ __align__(16) bf16_t sB[2][BNT * TBK];

    const int tid  = threadIdx.x;
    const int lane = tid & 63;
    const int wave = tid >> 6;
    const int wm   = wave / NWN;
    const int wn   = wave % NWN;
    const int bm   = blockIdx.x * BM;
    const int bn   = blockIdx.y * BNT;

    f32x4 acc[MT][NTW];
#pragma unroll
    for (int i = 0; i < MT; ++i)
#pragma unroll
        for (int j = 0; j < NTW; ++j) acc[i][j] = (f32x4){0.f, 0.f, 0.f, 0.f};

    // staging map: chunk c = l*THREADS+tid -> LDS row c/CPR, LDS chunk c%CPR,
    // LDS offset c*16B (linear). SOURCE chunk = (c%CPR) ^ foldf(row) so that
    // LDS[row][chunk] holds logical chunk (chunk ^ foldf(row)).
    const bf16_t* gA[AL];
    const bf16_t* gB[BL];
#pragma unroll
    for (int l = 0; l < AL; ++l) {
        const int c  = l * THREADS + tid;
        const int rL = c / CPR;
        const int sc = (c & (CPR - 1)) ^ foldf<CPR>(rL);
        gA[l] = A + (size_t)(bm + rL) * lda + sc * 8;
    }
#pragma unroll
    for (int l = 0; l < BL; ++l) {
        const int c  = l * THREADS + tid;
        const int rL = c / CPR;
        const int sc = (c & (CPR - 1)) ^ foldf<CPR>(rL);
        int rb = bn + rL;
        if (CLAMPN) rb = min(rb, N - 1);
        gB[l] = B + (size_t)rb * ldb + sc * 8;
    }

    auto stage = [&](int buf, int k0) {
#pragma unroll
        for (int l = 0; l < AL; ++l)
            gl_lds16(gA[l] + k0, &sA[buf][(size_t)(l * THREADS + tid) * 8]);
#pragma unroll
        for (int l = 0; l < BL; ++l)
            gl_lds16(gB[l] + k0, &sB[buf][(size_t)(l * THREADS + tid) * 8]);
    };

    const int mrow = lane & 15;
    const int q    = lane >> 4;
    // read-side swizzle: fragment rows are (mult of 16) + mrow, and foldf only
    // uses row bits [3:0] -> per-lane constant.
    const int swz = foldf<CPR>(mrow);
    const int qx  = q ^ (swz & 3);          // low 2 chunk bits
    const int ksw = swz >> 2;               // chunk bit 2 (CPR=8 only)

    stage(0, 0);
    int cur = 0;
    for (int k0 = 0; k0 < K; k0 += TBK) {
        if (k0 + TBK < K) {
            stage(cur ^ 1, k0 + TBK);   // next tile's DMA in flight across barrier
            vm_wait<L>();               // wait only for CURRENT tile's L loads
        } else {
            vm_wait<0>();               // epilogue drain
        }
        __builtin_amdgcn_s_barrier();   // all waves' DMA for buf[cur] landed
        asm volatile("" ::: "memory");  // don't hoist ds_reads above barrier

        int4v af[MT][KH], bv[NTW][KH];
        const bf16_t* pa = &sA[cur][(wm * 64 + mrow) * TBK + qx * 8];
        const bf16_t* pb = &sB[cur][(wn * (NTW * 16) + mrow) * TBK + qx * 8];
#pragma unroll
        for (int t = 0; t < MT; ++t)
#pragma unroll
            for (int kk = 0; kk < KH; ++kk)
                af[t][kk] = *(const int4v*)(pa + t * 16 * TBK + (kk ^ ksw) * 32);
#pragma unroll
        for (int t = 0; t < NTW; ++t)
#pragma unroll
            for (int kk = 0; kk < KH; ++kk)
                bv[t][kk] = *(const int4v*)(pb + t * 16 * TBK + (kk ^ ksw) * 32);
#pragma unroll
        for (int kk = 0; kk < KH; ++kk)       // logical k-order unchanged
#pragma unroll
            for (int mt = 0; mt < MT; ++mt)
#pragma unroll
                for (int nt = 0; nt < NTW; ++nt)
                    acc[mt][nt] = mfma16(af[mt][kk], bv[nt][kk], acc[mt][nt]);

        // all our ds_reads must COMPLETE before any wave passes the barrier
        // (next iter's DMA overwrites buf[cur]); MFMA sinking past is harmless.
        asm volatile("s_waitcnt lgkmcnt(0)" ::: "memory");
        __builtin_amdgcn_s_barrier();
        cur ^= 1;
    }

    int f = 0;
    if (MODE == 0) f = flag[0];

    // C/D layout: col = lane&15, row = (lane>>4)*4 + r   [m89/m91]
    const int coln = lane & 15;
    const int rq   = lane >> 4;
#pragma unroll
    for (int mt = 0; mt < MT; ++mt) {
#pragma unroll
        for (int r = 0; r < 4; ++r) {
            const int gm = bm + wm * 64 + mt * 16 + rq * 4 + r;
#pragma unroll
            for (int nt = 0; nt < NTW; ++nt) {
                const int gn = bn + wn * (NTW * 16) + nt * 16 + coln;
                const float c = acc[mt][nt][r];
                if (MODE == 0) {
                    if (gn < N) {
                        const size_t xi = (size_t)gm * N + gn;
                        const float xv = f ? ((const float*)Xin)[xi]
                                           : (float)((const bf16_t*)Xin)[xi];
                        Out[(size_t)gm * ldo + gn] = (bf16_t)(xv - c);
                    }
                } else if (MODE == 1) {
                    const size_t idx = (size_t)gm * ldo + gn;
                    const float uo = U[idx];
                    const float ao = fmaxf(uo - 0.3f, 0.0f);
                    const float un = uo + 0.01f * (c + ao - uo);
                    U[idx] = un;
                    Out[idx] = (bf16_t)fmaxf(un - 0.3f, 0.0f);
                } else {
                    if (gn < N)
                        Out[(size_t)gm * ldo + gn] = (bf16_t)c;
                }
            }
        }
    }
}

// fp32-output only: expand a (bf16, d_out scratch) into the fp32 a-region.
// Two passes with disjoint src/dst per pass (expansion-by-2 overlap split).
__global__ void a_move(const bf16_t* __restrict__ src, float* __restrict__ dst,
                       long lo, long hi, const int* __restrict__ flag) {
    if (!flag[0]) return;
    long i = lo + (long)blockIdx.x * 256 + threadIdx.x;
    if (i < hi) dst[i] = (float)src[i];
}

__global__ void recon_out(const bf16_t* __restrict__ rec, void* __restrict__ dout,
                          const int* __restrict__ flag) {
    long i = (long)blockIdx.x * 256 + threadIdx.x;
    if (i >= 6422528L) return;
    if (flag[0]) ((float*)dout)[i] = (float)rec[i];
    else         ((bf16_t*)dout)[i] = rec[i];
}

extern "C" void kernel_launch(void* const* d_in, const int* in_sizes, int n_in,
                              void* d_out, int out_size, void* d_ws, size_t ws_size,
                              hipStream_t stream) {
    const void* x = d_in[0];   // [8192, 784]  fp32 or bf16
    const void* w = d_in[1];   // [784, 2048]  fp32 or bf16
    (void)in_sizes; (void)n_in; (void)out_size; (void)ws_size;

    char* ws = (char*)d_ws;
    float*  u    = (float*)ws;                          // 67,108,864 B
    bf16_t* r    = (bf16_t*)(ws + 67108864);            // 13,107,200 B (8192x800)
    bf16_t* wT   = (bf16_t*)(ws + 80216064);            //  3,276,800 B (2048x800)
    bf16_t* wB   = (bf16_t*)(ws + 83492864);            //  3,211,264 B (784x2048)
    int*    flag = (int*)(ws + 86704128);               // total 86.7 MB
    bf16_t* aA   = (bf16_t*)((char*)d_out + 12845056);  // a scratch = bf16 a-region
    bf16_t* rec  = r;                                   // reuse r for recon temp

    sniff<<<1, 256, 0, stream>>>((const uint16_t*)w, flag);
    fill0<<<16384, 256, 0, stream>>>((int4v*)u, 4194304L);   // u = 0
    fill0<<<3200, 256, 0, stream>>>((int4v*)r, 819200L);     // r = 0 (incl. pad)
    fill0<<<8192, 256, 0, stream>>>((int4v*)aA, 2097152L);   // a = 0
    build_w<<<dim3(4, 2048), 256, 0, stream>>>(w, wT, wB, flag);

    // 99 LCA updates: r = x - a@w^T ; u += 0.01*(r@w + a - u); a = relu(u-0.3)
    for (int i = 0; i < 99; ++i) {
        gemm_nt<0, true, 128, 32, 8><<<dim3(64, 7), 512, 0, stream>>>(
            aA, wB, 784, 2048, 2048, 2048, x, nullptr, r, 800, flag);
        gemm_nt<1, false, 128, 32, 4><<<dim3(64, 16), 256, 0, stream>>>(
            r, wT, 2048, 800, 800, 800, nullptr, u, aA, 2048, flag);
    }

    // reconstruction = a @ w^T -> ws temp (bf16)
    gemm_nt<2, true, 128, 32, 8><<<dim3(64, 7), 512, 0, stream>>>(
        aA, wB, 784, 2048, 2048, 2048, nullptr, nullptr, rec, 784, flag);

    // fp32 out: move a into fp32 a-region (race-free 2-pass split at 5,177,344)
    float* aOutF = (float*)d_out + 6422528;
    a_move<<<45312, 256, 0, stream>>>(aA, aOutF, 5177344L, 16777216L, flag);
    a_move<<<20224, 256, 0, stream>>>(aA, aOutF, 0L, 5177344L, flag);

    // recon -> d_out front, flag dtype (aA scratch dead by now in fp32 mode)
    recon_out<<<25088, 256, 0, stream>>>(rec, d_out, flag);
}